// Round 1
// baseline (80.796 us; speedup 1.0000x reference)
//
#include <hip/hip_runtime.h>

// GMM NLL loss: B=4, N=4096, M=4096, scalar output (mean nll).
// Log2-domain, no max-subtraction (range-safe: lp2 in ~[-40,+20], sum*4096 << f32 max).
// Rank-6 expansion: lp = K2(n) + A(n)*txy2 + C(n)*tz2 + Bx(n)*tx + By(n)*ty + Cz(n)*tz
//   => 5 fma + exp2 + add per (n,m) pair.
//
// v2: no atomics, no memsets.
//  - NC=32, grid (128,2,4)=1024 blocks, __launch_bounds__(256,4) -> 4 waves/SIMD
//    (was 2) to hide LDS-broadcast latency + fma dep chains.
//  - Each block writes its 2048 partial sums with plain coalesced stores into
//    partials[b][chunk][m] (8 MB of d_ws, fully overwritten each launch -> no init).
//  - out[0] zeroed by one thread of gmm_partial; finalize (stream-ordered after)
//    accumulates via per-block atomicAdd.

constexpr int Bc = 4, Nc = 4096, Mc = 4096;
constexpr int NC = 32;                 // n-chunk per block
constexpr int NCHUNK = Nc / NC;        // 128
constexpr int TM = 8;                  // m values per thread
constexpr int THREADS = 256;
constexpr int MTILE = THREADS * TM;    // 2048 m per block

#define EPS 1e-8f
constexpr float LOG2E   = 1.4426950408889634f;
constexpr float LN2     = 0.6931471805599453f;
constexpr float LOG_2PI = 1.8378762043478343f;   // ln(2*3.14159), matches reference
constexpr float K_CONST = -1.5f * LOG_2PI * LOG2E;

__global__ __launch_bounds__(THREADS, 4) void gmm_partial(
    const float* __restrict__ pred_xyz,   // (B,N,3)
    const float* __restrict__ pred_sigma, // (B,N,2)
    const float* __restrict__ target,     // (B,M,3)
    float* __restrict__ partials,         // (B, NCHUNK, M) in d_ws
    float* __restrict__ out)              // scalar output, zeroed here
{
    __shared__ float4 lds4[NC];   // per n: K2, A, C, Bx
    __shared__ float2 lds2[NC];   // per n: By, Cz

    const int nck = blockIdx.x;
    const int mt  = blockIdx.y;
    const int b   = blockIdx.z;
    const int tid = threadIdx.x;
    const int n0  = nck * NC;

    // Zero the scalar output once; all gmm_partial blocks complete before
    // gmm_finalize launches (stream order), so this is race-free.
    if (nck == 0 && mt == 0 && b == 0 && tid == 0) out[0] = 0.f;

    // Per-n transform into LDS (32 lanes active; amortized over 2048 m)
    if (tid < NC) {
        const int n = n0 + tid;
        const float* pp = pred_xyz + ((size_t)b * Nc + n) * 3;
        const float px = pp[0], py = pp[1], pz = pp[2];
        const float* ps = pred_sigma + ((size_t)b * Nc + n) * 2;
        const float sxy = ps[0] + EPS;
        const float sz  = ps[1] + EPS;
        const float A  = -0.5f * LOG2E * __builtin_amdgcn_rcpf(sxy);
        const float C  = -0.5f * LOG2E * __builtin_amdgcn_rcpf(sz);
        const float k2 = -__builtin_amdgcn_logf(sxy)          // v_log_f32 = log2
                         - 0.5f * __builtin_amdgcn_logf(sz)
                         + K_CONST;
        const float K2 = k2 + A * (px * px + py * py) + C * (pz * pz);
        const float Bx = -2.f * A * px;
        const float By = -2.f * A * py;
        const float Cz = -2.f * C * pz;
        lds4[tid] = make_float4(K2, A, C, Bx);
        lds2[tid] = make_float2(By, Cz);
    }
    __syncthreads();

    // Per-thread target registers (fixed for whole block)
    float tx[TM], ty[TM], tz[TM], txy2[TM], tz2[TM], acc[TM];
    const int m0 = mt * MTILE;
#pragma unroll
    for (int j = 0; j < TM; ++j) {
        const int m = m0 + j * THREADS + tid;
        const float* tp = target + ((size_t)b * Mc + m) * 3;
        tx[j] = tp[0]; ty[j] = tp[1]; tz[j] = tp[2];
        txy2[j] = tx[j] * tx[j] + ty[j] * ty[j];
        tz2[j]  = tz[j] * tz[j];
        acc[j] = 0.f;
    }

    // Main loop: wave-uniform LDS broadcast reads; 8 independent chains per n.
#pragma unroll 4
    for (int i = 0; i < NC; ++i) {
        const float4 r0 = lds4[i];       // K2, A, C, Bx
        const float2 r1 = lds2[i];       // By, Cz
#pragma unroll
        for (int j = 0; j < TM; ++j) {
            float lp = fmaf(r0.y, txy2[j], r0.x);   // K2 + A*txy2
            lp = fmaf(r0.z, tz2[j], lp);            // + C*tz2
            lp = fmaf(r0.w, tx[j], lp);             // + Bx*tx
            lp = fmaf(r1.x, ty[j], lp);             // + By*ty
            lp = fmaf(r1.y, tz[j], lp);             // + Cz*tz
            acc[j] += __builtin_amdgcn_exp2f(lp);
        }
    }

    // Plain coalesced stores: block's 2048 partials are contiguous.
    float* dst = partials + ((size_t)b * NCHUNK + nck) * Mc + m0;
#pragma unroll
    for (int j = 0; j < TM; ++j)
        dst[j * THREADS + tid] = acc[j];
}

// Finalize: 64 blocks x 256 threads; thread t handles (b,m) = (t>>12, t&4095).
// For fixed chunk, consecutive lanes read consecutive m -> coalesced.
__global__ __launch_bounds__(256) void gmm_finalize(
    const float* __restrict__ partials, float* __restrict__ out)
{
    const int t = blockIdx.x * 256 + threadIdx.x;
    const int b = t >> 12;
    const int m = t & (Mc - 1);
    const float* src = partials + (size_t)b * NCHUNK * Mc + m;

    float s = 0.f;
#pragma unroll 8
    for (int c = 0; c < NCHUNK; ++c)
        s += src[(size_t)c * Mc];

    float local = __builtin_amdgcn_logf(s);   // log2(sum)
#pragma unroll
    for (int off = 32; off > 0; off >>= 1)
        local += __shfl_down(local, off, 64);

    __shared__ float w[4];
    const int wave = threadIdx.x >> 6;
    if ((threadIdx.x & 63) == 0) w[wave] = local;
    __syncthreads();
    if (threadIdx.x == 0) {
        const float tot = w[0] + w[1] + w[2] + w[3];
        // nll_i = -ln2 * log2(sum_i); mean over B*M
        atomicAdd(out, -LN2 / (float)(Bc * Mc) * tot);
    }
}

extern "C" void kernel_launch(void* const* d_in, const int* in_sizes, int n_in,
                              void* d_out, int out_size, void* d_ws, size_t ws_size,
                              hipStream_t stream) {
    const float* pred_xyz   = (const float*)d_in[0];
    const float* pred_sigma = (const float*)d_in[1];
    const float* target     = (const float*)d_in[2];
    float* out      = (float*)d_out;
    float* partials = (float*)d_ws;   // B*NCHUNK*M floats = 8 MB

    dim3 grid(NCHUNK, Mc / MTILE, Bc);   // (128, 2, 4) = 1024 blocks
    gmm_partial<<<grid, THREADS, 0, stream>>>(pred_xyz, pred_sigma, target,
                                              partials, out);
    gmm_finalize<<<Bc * Mc / 256, 256, 0, stream>>>(partials, out);
}

// Round 2
// 71.212 us; speedup vs baseline: 1.1346x; 1.1346x over previous
//
#include <hip/hip_runtime.h>

// GMM NLL loss: B=4, N=4096, M=4096, scalar output (mean nll).
// v3: MFMA formulation. lp2[n][m] = vn . vm  (6-term dot, log2-domain)
//   vn = [K2, A2, C2, Bx, By, Cz]  (per pred n)
//   vm = [1, txy2, tz2, tx, ty, tz] (per target m)
// Each f32 operand split into bf16 hi+lo; K-slots (18 of 32 used):
//   A (n-side) slots: [nh0..5, nh0..5, nl0..5, 0 x14]
//   B (m-side) slots: [mh0..5, ml0..5, mh0..5, 0 x14]
// => products nh*mh + nh*ml + nl*mh  (drops nl*ml ~ 2^-18 rel).
// D[n][m] from mfma_f32_16x16x32_bf16: col=lane&15 (m), row=(lane>>4)*4+reg (n).
// Per lane: acc += exp2(d[0..3]) over all n-tiles; shfl_xor(16,32) folds the
// 4 row-groups; lanes 0-15 store per-m partial sums. Finalize sums NSPLIT
// chunks, log2, mean.

constexpr int Bc = 4, Nc = 4096, Mc = 4096;
constexpr int NSPLIT  = 8;             // n split across blocks
constexpr int NCHUNK  = Nc / NSPLIT;   // 512 n per block
constexpr int NTILES  = NCHUNK / 16;   // 32 mfma iterations
constexpr int THREADS = 256;           // 4 waves
constexpr int MBLK    = 64;            // 64 m per block (16 per wave)
constexpr int REC     = 40;            // shorts per n-record (80 B, 16B-aligned)

#define EPS 1e-8f
constexpr float LOG2E   = 1.4426950408889634f;
constexpr float LN2     = 0.6931471805599453f;
constexpr float LOG_2PI = 1.8378762043478343f;   // ln(2*3.14159), matches reference
constexpr float K_CONST = -1.5f * LOG_2PI * LOG2E;

typedef __attribute__((ext_vector_type(8))) short bf16x8;
typedef __attribute__((ext_vector_type(4))) float f32x4;
typedef unsigned int   u32;
typedef unsigned short u16;

static __device__ __forceinline__ u16 f2bf(float x) {    // RNE f32 -> bf16 bits
    u32 u = __float_as_uint(x);
    return (u16)((u + 0x7fffu + ((u >> 16) & 1u)) >> 16);
}
static __device__ __forceinline__ float bf2f(u16 h) {
    return __uint_as_float((u32)h << 16);
}

__global__ __launch_bounds__(THREADS) void gmm_partial(
    const float* __restrict__ pred_xyz,   // (B,N,3)
    const float* __restrict__ pred_sigma, // (B,N,2)
    const float* __restrict__ target,     // (B,M,3)
    float* __restrict__ partials,         // (B, NSPLIT, M)
    float* __restrict__ out)
{
    __shared__ short lds[NCHUNK * REC];   // 40 KB -> 4 blocks/CU

    const int mblk = blockIdx.x;   // 0..63  (m tile)
    const int nck  = blockIdx.y;   // 0..7   (n chunk)
    const int b    = blockIdx.z;
    const int tid  = threadIdx.x;

    if (mblk == 0 && nck == 0 && b == 0 && tid == 0) out[0] = 0.f;

    // ---- phase 1: n-coefs -> bf16 hi/lo records in LDS (2 n per thread) ----
    for (int t = tid; t < NCHUNK; t += THREADS) {
        const int n = nck * NCHUNK + t;
        const float* pp = pred_xyz + ((size_t)b * Nc + n) * 3;
        const float px = pp[0], py = pp[1], pz = pp[2];
        const float* ps = pred_sigma + ((size_t)b * Nc + n) * 2;
        const float sxy = ps[0] + EPS;
        const float sz  = ps[1] + EPS;
        const float A2 = -0.5f * LOG2E * __builtin_amdgcn_rcpf(sxy);
        const float C2 = -0.5f * LOG2E * __builtin_amdgcn_rcpf(sz);
        const float K2 = K_CONST - __builtin_amdgcn_logf(sxy)
                         - 0.5f * __builtin_amdgcn_logf(sz)
                         + A2 * (px * px + py * py) + C2 * (pz * pz);
        const float Bx = -2.f * A2 * px;
        const float By = -2.f * A2 * py;
        const float Cz = -2.f * C2 * pz;

        const u16 h0 = f2bf(K2), h1 = f2bf(A2), h2 = f2bf(C2),
                  h3 = f2bf(Bx), h4 = f2bf(By), h5 = f2bf(Cz);
        const u16 l0 = f2bf(K2 - bf2f(h0)), l1 = f2bf(A2 - bf2f(h1)),
                  l2 = f2bf(C2 - bf2f(h2)), l3 = f2bf(Bx - bf2f(h3)),
                  l4 = f2bf(By - bf2f(h4)), l5 = f2bf(Cz - bf2f(h5));

        const u32 d0 = (u32)h0 | ((u32)h1 << 16);
        const u32 d1 = (u32)h2 | ((u32)h3 << 16);
        const u32 d2 = (u32)h4 | ((u32)h5 << 16);
        const u32 e0 = (u32)l0 | ((u32)l1 << 16);
        const u32 e1 = (u32)l2 | ((u32)l3 << 16);
        const u32 e2 = (u32)l4 | ((u32)l5 << 16);
        u32* rec = (u32*)&lds[t * REC];
        rec[0] = d0; rec[1]  = d1; rec[2]  = d2;   // k0-5  : nh
        rec[3] = d0; rec[4]  = d1; rec[5]  = d2;   // k6-11 : nh
        rec[6] = e0; rec[7]  = e1; rec[8]  = e2;   // k12-17: nl
        rec[9] = 0;  rec[10] = 0;  rec[11] = 0;    // k18-31: must be 0
        rec[12] = 0; rec[13] = 0;  rec[14] = 0;  rec[15] = 0;
    }
    __syncthreads();

    // ---- B-fragment (m-side), fixed for whole kernel ----
    const int lane = tid & 63;
    const int wave = tid >> 6;
    const int g    = lane >> 4;           // k-group
    const int m    = mblk * MBLK + wave * 16 + (lane & 15);

    const float* tp = target + ((size_t)b * Mc + m) * 3;
    const float tx = tp[0], ty = tp[1], tz = tp[2];
    const float u1 = tx * tx + ty * ty, u2 = tz * tz;

    const u16 mh0 = f2bf(1.f), mh1 = f2bf(u1), mh2 = f2bf(u2),
              mh3 = f2bf(tx),  mh4 = f2bf(ty), mh5 = f2bf(tz);
    const u16 ml0 = 0,
              ml1 = f2bf(u1 - bf2f(mh1)), ml2 = f2bf(u2 - bf2f(mh2)),
              ml3 = f2bf(tx - bf2f(mh3)), ml4 = f2bf(ty - bf2f(mh4)),
              ml5 = f2bf(tz - bf2f(mh5));

    u16 s0, s1, s2, s3, s4, s5, s6, s7;
    if (g == 0)      { s0=mh0; s1=mh1; s2=mh2; s3=mh3; s4=mh4; s5=mh5; s6=ml0; s7=ml1; }
    else if (g == 1) { s0=ml2; s1=ml3; s2=ml4; s3=ml5; s4=mh0; s5=mh1; s6=mh2; s7=mh3; }
    else if (g == 2) { s0=mh4; s1=mh5; s2=0;   s3=0;   s4=0;   s5=0;   s6=0;   s7=0;   }
    else             { s0=0;   s1=0;   s2=0;   s3=0;   s4=0;   s5=0;   s6=0;   s7=0;   }
    bf16x8 bfrag;
    bfrag[0]=(short)s0; bfrag[1]=(short)s1; bfrag[2]=(short)s2; bfrag[3]=(short)s3;
    bfrag[4]=(short)s4; bfrag[5]=(short)s5; bfrag[6]=(short)s6; bfrag[7]=(short)s7;

    // ---- main loop: 1 ds_read_b128 + 1 MFMA + 4 exp2 + 4 add per 16 n ----
    float a0 = 0.f, a1 = 0.f, a2 = 0.f, a3 = 0.f;
    const short* abase = &lds[(lane & 15) * REC + g * 8];
    const f32x4 zero4 = {0.f, 0.f, 0.f, 0.f};
#pragma unroll 4
    for (int it = 0; it < NTILES; ++it) {
        bf16x8 afrag = *(const bf16x8*)(abase + it * 16 * REC);
        f32x4 d = __builtin_amdgcn_mfma_f32_16x16x32_bf16(afrag, bfrag, zero4, 0, 0, 0);
        a0 += __builtin_amdgcn_exp2f(d[0]);
        a1 += __builtin_amdgcn_exp2f(d[1]);
        a2 += __builtin_amdgcn_exp2f(d[2]);
        a3 += __builtin_amdgcn_exp2f(d[3]);
    }

    float s = (a0 + a1) + (a2 + a3);
    s += __shfl_xor(s, 16, 64);
    s += __shfl_xor(s, 32, 64);
    if (g == 0)
        partials[((size_t)(b * NSPLIT + nck)) * Mc + m] = s;
}

// Finalize: 64 blocks x 256 threads; thread t -> (b,m). Sum NSPLIT chunks,
// log2, wave+block reduce, one atomicAdd per block.
__global__ __launch_bounds__(256) void gmm_finalize(
    const float* __restrict__ partials, float* __restrict__ out)
{
    const int t = blockIdx.x * 256 + threadIdx.x;
    const int b = t >> 12;
    const int m = t & (Mc - 1);

    float sum = 0.f;
#pragma unroll
    for (int c = 0; c < NSPLIT; ++c)
        sum += partials[((size_t)(b * NSPLIT + c)) * Mc + m];

    float local = __builtin_amdgcn_logf(sum);   // log2(sum)
#pragma unroll
    for (int off = 32; off > 0; off >>= 1)
        local += __shfl_down(local, off, 64);

    __shared__ float w[4];
    const int wave = threadIdx.x >> 6;
    if ((threadIdx.x & 63) == 0) w[wave] = local;
    __syncthreads();
    if (threadIdx.x == 0) {
        const float tot = w[0] + w[1] + w[2] + w[3];
        atomicAdd(out, -LN2 / (float)(Bc * Mc) * tot);
    }
}

extern "C" void kernel_launch(void* const* d_in, const int* in_sizes, int n_in,
                              void* d_out, int out_size, void* d_ws, size_t ws_size,
                              hipStream_t stream) {
    const float* pred_xyz   = (const float*)d_in[0];
    const float* pred_sigma = (const float*)d_in[1];
    const float* target     = (const float*)d_in[2];
    float* out      = (float*)d_out;
    float* partials = (float*)d_ws;   // B*NSPLIT*M floats = 512 KB

    dim3 grid(Mc / MBLK, NSPLIT, Bc);   // (64, 8, 4) = 2048 blocks
    gmm_partial<<<grid, THREADS, 0, stream>>>(pred_xyz, pred_sigma, target,
                                              partials, out);
    gmm_finalize<<<Bc * Mc / 256, 256, 0, stream>>>(partials, out);
}